// Round 1
// baseline (665.992 us; speedup 1.0000x reference)
//
#include <hip/hip_runtime.h>

// MultiHeadedAttentionBlur on MI355X.
// Key trick: blur is linear over the key axis -> blur K once (12.6 MB)
// instead of the logits (402 MB). Then fused MFMA attention + softmax.
//
// ws layout (ushorts):
//   xb   [8192][768]      bf16 x
//   wb   [1536][768]      bf16 W rows 768..2303 (k then q chunks)
//   qh   [96][1024][64]   bf16 q heads, pre-scaled by 0.125
//   kh   [96][1024][64]   bf16 k heads
//   ktmp [96][1024][64]   vertical-blurred k
//   kt   [96][1024][64]   fully blurred k

typedef __attribute__((ext_vector_type(8))) short short8;
typedef __attribute__((ext_vector_type(4))) float f32x4;

__device__ __forceinline__ float bf2f(unsigned short u) {
    unsigned int v = ((unsigned int)u) << 16;
    return __builtin_bit_cast(float, v);
}
__device__ __forceinline__ unsigned short f2bf(float f) {
    unsigned int u = __builtin_bit_cast(unsigned int, f);
    u += 0x7FFFu + ((u >> 16) & 1u);   // round-to-nearest-even
    return (unsigned short)(u >> 16);
}

// ---------------- kernel 0: cast x and W[768:2304,:] to bf16 ----------------
__global__ __launch_bounds__(256) void k_cast(const float* __restrict__ x,
                                              const float* __restrict__ w,
                                              unsigned short* __restrict__ dst) {
    const int NX = 8 * 1024 * 768;                 // 6291456
    int i = (blockIdx.x * 256 + threadIdx.x) * 4;  // total 7471104 elems
    float4 v;
    if (i < NX) v = *(const float4*)(x + i);
    else        v = *(const float4*)(w + 768 * 768 + (i - NX));
    ushort4 o;
    o.x = f2bf(v.x); o.y = f2bf(v.y); o.z = f2bf(v.z); o.w = f2bf(v.w);
    *(ushort4*)(dst + i) = o;
}

// ---------------- kernel 1: projection GEMM (M=8192,N=1536,K=768) -----------
// Wave computes 16(m) x 64(n). Output scattered into head-major q/k arrays.
__global__ __launch_bounds__(256) void k_proj(const unsigned short* __restrict__ xb,
                                              const unsigned short* __restrict__ wb,
                                              unsigned short* __restrict__ qh,
                                              unsigned short* __restrict__ kh) {
    const int lane = threadIdx.x & 63;
    const int wv   = threadIdx.x >> 6;
    const int m0   = blockIdx.x * 64 + wv * 16;  // token tile base
    const int n0   = blockIdx.y * 64;            // f tile base (0..1535)
    const int col  = lane & 15;
    const int kq   = (lane >> 4) * 8;            // k-offset within 32-chunk

    f32x4 acc[4] = {};
    const unsigned short* ap = xb + (m0 + col) * 768 + kq;
    const unsigned short* bp = wb + (n0 + col) * 768 + kq;
    for (int kk = 0; kk < 768; kk += 32) {
        short8 a = *(const short8*)(const void*)(ap + kk);
#pragma unroll
        for (int nt = 0; nt < 4; ++nt) {
            short8 b = *(const short8*)(const void*)(bp + nt * 16 * 768 + kk);
            acc[nt] = __builtin_amdgcn_mfma_f32_16x16x32_bf16(a, b, acc[nt], 0, 0, 0);
        }
    }
#pragma unroll
    for (int nt = 0; nt < 4; ++nt) {
        int f = n0 + nt * 16 + col;
        bool isq = (f >= 768);
        int fl = isq ? (f - 768) : f;
        int h = fl >> 6, d = fl & 63;
        unsigned short* dstb = isq ? qh : kh;
        float scl = isq ? 0.125f : 1.0f;   // fold SCALE into q
#pragma unroll
        for (int i = 0; i < 4; ++i) {
            int t = m0 + (lane >> 4) * 4 + i;                 // token
            int n = (t >> 10) * 12 + h;                       // head index b*12+h
            dstb[((n << 10) + (t & 1023)) * 64 + d] = f2bf(acc[nt][i] * scl);
        }
    }
}

// ---------------- kernel 2: separable gaussian blur of K over key grid ------
template <int VERT>
__global__ __launch_bounds__(256) void k_blur(const unsigned short* __restrict__ src,
                                              unsigned short* __restrict__ dst) {
    int t  = blockIdx.x * 256 + threadIdx.x;  // 96*1024*16 threads, 4 ch each
    int dq = t & 15;
    int sk = (t >> 4) & 1023;
    int n  = t >> 14;
    int r = sk >> 5, c = sk & 31;
    const float g[5] = {0.054488684f, 0.24420134f, 0.40261995f, 0.24420134f, 0.054488684f};
    float acc0 = 0.f, acc1 = 0.f, acc2 = 0.f, acc3 = 0.f;
#pragma unroll
    for (int o = -2; o <= 2; ++o) {
        int p = (VERT ? r : c) + o;
        if (p < 0)  p = -p;        // reflect (no edge repeat)
        if (p > 31) p = 62 - p;
        int sk2 = VERT ? (p * 32 + c) : (r * 32 + p);
        const unsigned short* sp = src + ((n << 10) + sk2) * 64 + dq * 4;
        uint2 u = *(const uint2*)(const void*)sp;
        float w = g[o + 2];
        acc0 += w * bf2f((unsigned short)(u.x & 0xffff));
        acc1 += w * bf2f((unsigned short)(u.x >> 16));
        acc2 += w * bf2f((unsigned short)(u.y & 0xffff));
        acc3 += w * bf2f((unsigned short)(u.y >> 16));
    }
    uint2 ov;
    ov.x = (unsigned)f2bf(acc0) | ((unsigned)f2bf(acc1) << 16);
    ov.y = (unsigned)f2bf(acc2) | ((unsigned)f2bf(acc3) << 16);
    *(uint2*)(void*)(dst + ((n << 10) + sk) * 64 + dq * 4) = ov;
}

// ---------------- kernel 3: fused attention (logits + softmax + store) ------
// Block: 16 queries of one head. Wave w owns keys [w*256, w*256+256).
__global__ __launch_bounds__(256) void k_attn(const unsigned short* __restrict__ qh,
                                              const unsigned short* __restrict__ kt,
                                              float* __restrict__ out) {
    const int lane = threadIdx.x & 63;
    const int wv   = threadIdx.x >> 6;
    const int n    = blockIdx.y;
    const int s0   = blockIdx.x * 16;
    const int col  = lane & 15;
    const int kq   = (lane >> 4) * 8;

    __shared__ float red[2][4][16];   // [max/sum][wave][query]

    const unsigned short* qp = qh + ((n << 10) + s0 + col) * 64 + kq;
    short8 a0 = *(const short8*)(const void*)(qp);
    short8 a1 = *(const short8*)(const void*)(qp + 32);

    f32x4 acc[16];
    const unsigned short* kp = kt + ((n << 10) + wv * 256 + col) * 64 + kq;
#pragma unroll
    for (int t = 0; t < 16; ++t) {
        short8 b0 = *(const short8*)(const void*)(kp + t * 1024);
        short8 b1 = *(const short8*)(const void*)(kp + t * 1024 + 32);
        f32x4 c = {};
        c = __builtin_amdgcn_mfma_f32_16x16x32_bf16(a0, b0, c, 0, 0, 0);
        c = __builtin_amdgcn_mfma_f32_16x16x32_bf16(a1, b1, c, 0, 0, 0);
        acc[t] = c;
    }

    // per-query max over this wave's 256 keys
    float mx[4];
#pragma unroll
    for (int i = 0; i < 4; ++i) {
        float m = acc[0][i];
#pragma unroll
        for (int t = 1; t < 16; ++t) m = fmaxf(m, acc[t][i]);
#pragma unroll
        for (int off = 1; off < 16; off <<= 1) m = fmaxf(m, __shfl_xor(m, off, 64));
        mx[i] = m;
    }
    if (col == 0) {
#pragma unroll
        for (int i = 0; i < 4; ++i) red[0][wv][(lane >> 4) * 4 + i] = mx[i];
    }
    __syncthreads();

    float sm[4];
#pragma unroll
    for (int i = 0; i < 4; ++i) {
        int qloc = (lane >> 4) * 4 + i;
        float m = fmaxf(fmaxf(red[0][0][qloc], red[0][1][qloc]),
                        fmaxf(red[0][2][qloc], red[0][3][qloc]));
        float s = 0.f;
#pragma unroll
        for (int t = 0; t < 16; ++t) {
            float e = __expf(acc[t][i] - m);
            acc[t][i] = e;
            s += e;
        }
#pragma unroll
        for (int off = 1; off < 16; off <<= 1) s += __shfl_xor(s, off, 64);
        sm[i] = s;
    }
    if (col == 0) {
#pragma unroll
        for (int i = 0; i < 4; ++i) red[1][wv][(lane >> 4) * 4 + i] = sm[i];
    }
    __syncthreads();

#pragma unroll
    for (int i = 0; i < 4; ++i) {
        int qloc = (lane >> 4) * 4 + i;
        float s = red[1][0][qloc] + red[1][1][qloc] + red[1][2][qloc] + red[1][3][qloc];
        float inv = 1.0f / s;
        float* op = out + (((size_t)(n << 10) + s0 + qloc) << 10) + wv * 256 + col;
#pragma unroll
        for (int t = 0; t < 16; ++t) op[t * 16] = acc[t][i] * inv;
    }
}

extern "C" void kernel_launch(void* const* d_in, const int* in_sizes, int n_in,
                              void* d_out, int out_size, void* d_ws, size_t ws_size,
                              hipStream_t stream) {
    const float* x = (const float*)d_in[0];
    const float* W = (const float*)d_in[1];
    float* out = (float*)d_out;

    unsigned short* ws   = (unsigned short*)d_ws;
    unsigned short* xb   = ws;                 // 6291456
    unsigned short* wb   = xb + 6291456;       // 1179648 (contiguous with xb)
    unsigned short* qh   = wb + 1179648;       // 6291456
    unsigned short* kh   = qh + 6291456;       // 6291456
    unsigned short* ktmp = kh + 6291456;       // 6291456
    unsigned short* kt   = ktmp + 6291456;     // 6291456  (total ~65.3 MB)

    k_cast<<<7296, 256, 0, stream>>>(x, W, xb);                 // xb+wb contiguous
    k_proj<<<dim3(128, 24), 256, 0, stream>>>(xb, wb, qh, kh);
    k_blur<1><<<6144, 256, 0, stream>>>(kh, ktmp);              // vertical
    k_blur<0><<<6144, 256, 0, stream>>>(ktmp, kt);              // horizontal
    k_attn<<<dim3(64, 96), 256, 0, stream>>>(qh, kt, out);
}

// Round 2
// 538.381 us; speedup vs baseline: 1.2370x; 1.2370x over previous
//
#include <hip/hip_runtime.h>

// MultiHeadedAttentionBlur on MI355X.
// Key trick: blur is linear over the key axis -> blur K once (12.6 MB)
// instead of the logits (402 MB). Then fused MFMA attention + softmax.
// Round 1: LDS-tiled projection GEMM (global_load_lds w16 + XOR swizzle),
//          exp2-domain softmax (fold 0.125*log2e into q).
//
// ws layout (ushorts):
//   xb   [8192][768]      bf16 x
//   wb   [1536][768]      bf16 W rows 768..2303 (k then q chunks)
//   qh   [96][1024][64]   bf16 q heads, pre-scaled by 0.125*log2(e)
//   kh   [96][1024][64]   bf16 k heads
//   ktmp [96][1024][64]   vertical-blurred k
//   kt   [96][1024][64]   fully blurred k

typedef __attribute__((ext_vector_type(8))) short short8;
typedef __attribute__((ext_vector_type(4))) float f32x4;

__device__ __forceinline__ float bf2f(unsigned short u) {
    unsigned int v = ((unsigned int)u) << 16;
    return __builtin_bit_cast(float, v);
}
__device__ __forceinline__ unsigned short f2bf(float f) {
    unsigned int u = __builtin_bit_cast(unsigned int, f);
    u += 0x7FFFu + ((u >> 16) & 1u);   // round-to-nearest-even
    return (unsigned short)(u >> 16);
}

__device__ __forceinline__ void g2lds16(const unsigned short* g, unsigned short* l) {
    __builtin_amdgcn_global_load_lds(
        (const __attribute__((address_space(1))) void*)g,
        (__attribute__((address_space(3))) void*)l, 16, 0, 0);
}

#if defined(__has_builtin) && __has_builtin(__builtin_amdgcn_exp2f)
#define EXP2F(x) __builtin_amdgcn_exp2f(x)
#else
#define EXP2F(x) exp2f(x)
#endif

// 0.125 (SCALE) * log2(e): softmax done in exp2 domain, saves a mul per elem.
#define QSCALE 0.1803368801111204f

// ---------------- kernel 0: cast x and W[768:2304,:] to bf16 ----------------
__global__ __launch_bounds__(256) void k_cast(const float* __restrict__ x,
                                              const float* __restrict__ w,
                                              unsigned short* __restrict__ dst) {
    const int NX = 8 * 1024 * 768;                 // 6291456
    int i = (blockIdx.x * 256 + threadIdx.x) * 4;  // total 7471104 elems
    float4 v;
    if (i < NX) v = *(const float4*)(x + i);
    else        v = *(const float4*)(w + 768 * 768 + (i - NX));
    ushort4 o;
    o.x = f2bf(v.x); o.y = f2bf(v.y); o.z = f2bf(v.z); o.w = f2bf(v.w);
    *(ushort4*)(dst + i) = o;
}

// ---------------- kernel 1: projection GEMM (M=8192,N=1536,K=768) -----------
// 128x128 block tile, BK=64, global_load_lds w16 staging, XOR chunk swizzle
// (swizzle applied to the GLOBAL source address since LDS dest is lane-fixed).
// 4 waves in 2x2, each computing 64x64 via 4x4 MFMA 16x16x32 tiles.
__global__ __launch_bounds__(256) void k_proj(const unsigned short* __restrict__ xb,
                                              const unsigned short* __restrict__ wb,
                                              unsigned short* __restrict__ qh,
                                              unsigned short* __restrict__ kh) {
    __shared__ unsigned short As[128 * 64];   // 16 KB, row-major [row][64], no pad
    __shared__ unsigned short Bs[128 * 64];   // 16 KB

    const int lane = threadIdx.x & 63;
    const int wv   = threadIdx.x >> 6;
    const int m0   = blockIdx.x * 128;   // token tile base
    const int n0   = blockIdx.y * 128;   // feature tile base (0..1535)
    const int col  = lane & 15;
    const int quad = lane >> 4;
    const int wm   = (wv >> 1) * 64;
    const int wn   = (wv & 1) * 64;

    // staging: wave wv owns rows [wv*32, wv*32+32); instr j covers 8 rows.
    // lane -> row wv*32 + j*8 + (lane>>3), physical chunk lane&7 (16B).
    // physical chunk p holds logical chunk p ^ (row&7)  (bank-conflict swizzle)
    const int srow   = wv * 32 + (lane >> 3);
    const int schunk = ((lane & 7) ^ ((lane >> 3) & 7)) * 8;  // shorts
    const unsigned short* ag = xb + (size_t)(m0 + srow) * 768 + schunk;
    const unsigned short* bg = wb + (size_t)(n0 + srow) * 768 + schunk;
    unsigned short* al = As + (wv * 32) * 64;   // wave-uniform LDS base
    unsigned short* bl = Bs + (wv * 32) * 64;

    f32x4 acc[4][4] = {};

    for (int kk = 0; kk < 768; kk += 64) {
        __syncthreads();   // previous iter's LDS reads done
#pragma unroll
        for (int j = 0; j < 4; ++j) {
            g2lds16(ag + j * 8 * 768 + kk, al + j * 8 * 64);
            g2lds16(bg + j * 8 * 768 + kk, bl + j * 8 * 64);
        }
        __syncthreads();   // staging visible

#pragma unroll
        for (int kc = 0; kc < 2; ++kc) {
            const int ch = ((kc * 4 + quad) ^ (col & 7)) * 8;  // swizzled 16B chunk
            short8 a[4], b[4];
#pragma unroll
            for (int mt = 0; mt < 4; ++mt)
                a[mt] = *(const short8*)(const void*)(As + (wm + mt * 16 + col) * 64 + ch);
#pragma unroll
            for (int nt = 0; nt < 4; ++nt)
                b[nt] = *(const short8*)(const void*)(Bs + (wn + nt * 16 + col) * 64 + ch);
#pragma unroll
            for (int mt = 0; mt < 4; ++mt)
#pragma unroll
                for (int nt = 0; nt < 4; ++nt)
                    acc[mt][nt] = __builtin_amdgcn_mfma_f32_16x16x32_bf16(
                        a[mt], b[nt], acc[mt][nt], 0, 0, 0);
        }
    }

    // epilogue: scatter into head-major q/k arrays; fold QSCALE into q.
#pragma unroll
    for (int nt = 0; nt < 4; ++nt) {
        int f = n0 + wn + nt * 16 + col;
        bool isq = (f >= 768);
        int fl = isq ? (f - 768) : f;
        int h = fl >> 6, d = fl & 63;
        unsigned short* dstb = isq ? qh : kh;
        float scl = isq ? QSCALE : 1.0f;
#pragma unroll
        for (int mt = 0; mt < 4; ++mt) {
#pragma unroll
            for (int i = 0; i < 4; ++i) {
                int t = m0 + wm + mt * 16 + quad * 4 + i;   // token
                int n = (t >> 10) * 12 + h;                 // head index b*12+h
                dstb[((n << 10) + (t & 1023)) * 64 + d] = f2bf(acc[mt][nt][i] * scl);
            }
        }
    }
}

// ---------------- kernel 2: separable gaussian blur of K over key grid ------
template <int VERT>
__global__ __launch_bounds__(256) void k_blur(const unsigned short* __restrict__ src,
                                              unsigned short* __restrict__ dst) {
    int t  = blockIdx.x * 256 + threadIdx.x;  // 96*1024*16 threads, 4 ch each
    int dq = t & 15;
    int sk = (t >> 4) & 1023;
    int n  = t >> 14;
    int r = sk >> 5, c = sk & 31;
    const float g[5] = {0.054488684f, 0.24420134f, 0.40261995f, 0.24420134f, 0.054488684f};
    float acc0 = 0.f, acc1 = 0.f, acc2 = 0.f, acc3 = 0.f;
#pragma unroll
    for (int o = -2; o <= 2; ++o) {
        int p = (VERT ? r : c) + o;
        if (p < 0)  p = -p;        // reflect (no edge repeat)
        if (p > 31) p = 62 - p;
        int sk2 = VERT ? (p * 32 + c) : (r * 32 + p);
        const unsigned short* sp = src + ((n << 10) + sk2) * 64 + dq * 4;
        uint2 u = *(const uint2*)(const void*)sp;
        float w = g[o + 2];
        acc0 += w * bf2f((unsigned short)(u.x & 0xffff));
        acc1 += w * bf2f((unsigned short)(u.x >> 16));
        acc2 += w * bf2f((unsigned short)(u.y & 0xffff));
        acc3 += w * bf2f((unsigned short)(u.y >> 16));
    }
    uint2 ov;
    ov.x = (unsigned)f2bf(acc0) | ((unsigned)f2bf(acc1) << 16);
    ov.y = (unsigned)f2bf(acc2) | ((unsigned)f2bf(acc3) << 16);
    *(uint2*)(void*)(dst + ((n << 10) + sk) * 64 + dq * 4) = ov;
}

// ---------------- kernel 3: fused attention (logits + softmax + store) ------
// Block: 16 queries of one head. Wave w owns keys [w*256, w*256+256).
// Logits arrive pre-scaled by log2(e) -> softmax via native v_exp_f32 (2^x).
__global__ __launch_bounds__(256) void k_attn(const unsigned short* __restrict__ qh,
                                              const unsigned short* __restrict__ kt,
                                              float* __restrict__ out) {
    const int lane = threadIdx.x & 63;
    const int wv   = threadIdx.x >> 6;
    const int n    = blockIdx.y;
    const int s0   = blockIdx.x * 16;
    const int col  = lane & 15;
    const int kq   = (lane >> 4) * 8;

    __shared__ float red[2][4][16];   // [max/sum][wave][query]

    const unsigned short* qp = qh + ((n << 10) + s0 + col) * 64 + kq;
    short8 a0 = *(const short8*)(const void*)(qp);
    short8 a1 = *(const short8*)(const void*)(qp + 32);

    f32x4 acc[16];
    const unsigned short* kp = kt + ((n << 10) + wv * 256 + col) * 64 + kq;
#pragma unroll
    for (int t = 0; t < 16; ++t) {
        short8 b0 = *(const short8*)(const void*)(kp + t * 1024);
        short8 b1 = *(const short8*)(const void*)(kp + t * 1024 + 32);
        f32x4 c = {};
        c = __builtin_amdgcn_mfma_f32_16x16x32_bf16(a0, b0, c, 0, 0, 0);
        c = __builtin_amdgcn_mfma_f32_16x16x32_bf16(a1, b1, c, 0, 0, 0);
        acc[t] = c;
    }

    // per-query max over this wave's 256 keys
    float mx[4];
#pragma unroll
    for (int i = 0; i < 4; ++i) {
        float m = acc[0][i];
#pragma unroll
        for (int t = 1; t < 16; ++t) m = fmaxf(m, acc[t][i]);
#pragma unroll
        for (int off = 1; off < 16; off <<= 1) m = fmaxf(m, __shfl_xor(m, off, 64));
        mx[i] = m;
    }
    if (col == 0) {
#pragma unroll
        for (int i = 0; i < 4; ++i) red[0][wv][(lane >> 4) * 4 + i] = mx[i];
    }
    __syncthreads();

    float sm[4];
#pragma unroll
    for (int i = 0; i < 4; ++i) {
        int qloc = (lane >> 4) * 4 + i;
        float m = fmaxf(fmaxf(red[0][0][qloc], red[0][1][qloc]),
                        fmaxf(red[0][2][qloc], red[0][3][qloc]));
        float s = 0.f;
#pragma unroll
        for (int t = 0; t < 16; ++t) {
            float e = EXP2F(acc[t][i] - m);   // logits already in log2e domain
            acc[t][i] = e;
            s += e;
        }
#pragma unroll
        for (int off = 1; off < 16; off <<= 1) s += __shfl_xor(s, off, 64);
        sm[i] = s;
    }
    if (col == 0) {
#pragma unroll
        for (int i = 0; i < 4; ++i) red[1][wv][(lane >> 4) * 4 + i] = sm[i];
    }
    __syncthreads();

#pragma unroll
    for (int i = 0; i < 4; ++i) {
        int qloc = (lane >> 4) * 4 + i;
        float s = red[1][0][qloc] + red[1][1][qloc] + red[1][2][qloc] + red[1][3][qloc];
        float inv = 1.0f / s;
        float* op = out + (((size_t)(n << 10) + s0 + qloc) << 10) + wv * 256 + col;
#pragma unroll
        for (int t = 0; t < 16; ++t) op[t * 16] = acc[t][i] * inv;
    }
}

extern "C" void kernel_launch(void* const* d_in, const int* in_sizes, int n_in,
                              void* d_out, int out_size, void* d_ws, size_t ws_size,
                              hipStream_t stream) {
    const float* x = (const float*)d_in[0];
    const float* W = (const float*)d_in[1];
    float* out = (float*)d_out;

    unsigned short* ws   = (unsigned short*)d_ws;
    unsigned short* xb   = ws;                 // 6291456
    unsigned short* wb   = xb + 6291456;       // 1179648 (contiguous with xb)
    unsigned short* qh   = wb + 1179648;       // 6291456
    unsigned short* kh   = qh + 6291456;       // 6291456
    unsigned short* ktmp = kh + 6291456;       // 6291456
    unsigned short* kt   = ktmp + 6291456;     // 6291456  (total ~65.3 MB)

    k_cast<<<7296, 256, 0, stream>>>(x, W, xb);                 // xb+wb contiguous
    k_proj<<<dim3(64, 12), 256, 0, stream>>>(xb, wb, qh, kh);
    k_blur<1><<<6144, 256, 0, stream>>>(kh, ktmp);              // vertical
    k_blur<0><<<6144, 256, 0, stream>>>(ktmp, kt);              // horizontal
    k_attn<<<dim3(64, 96), 256, 0, stream>>>(qh, kt, out);
}